// Round 5
// baseline (161.921 us; speedup 1.0000x reference)
//
#include <hip/hip_runtime.h>
#include <math.h>

#define Q_TOT 10000
#define NVIEW 6
#define NTOK  2442
#define HP_   37
#define WP_   66
#define CD_   768
#define CC_   256
#define NH_   8
#define NP_   4
#define HD_   32

typedef __attribute__((ext_vector_type(8))) short bf16x8;
typedef __attribute__((ext_vector_type(4))) float f32x4;

__device__ inline unsigned short f2bf(float f) {
    unsigned u = __builtin_bit_cast(unsigned, f);
    unsigned r = u + 0x7FFFu + ((u >> 16) & 1u);
    return (unsigned short)(r >> 16);
}

// ---------------- W2 = vp_w(256,256) @ proj_w(256,768), output bf16 ----------------
__global__ __launch_bounds__(256) void w2_kernel(const float* __restrict__ vp_w,
                                                 const float* __restrict__ proj_w,
                                                 unsigned short* __restrict__ W2b) {
    int b = blockIdx.x;            // 0..767
    int o2 = b / 3;
    int c = (b % 3) * 256 + threadIdx.x;
    __shared__ float vps[256];
    vps[threadIdx.x] = vp_w[(size_t)o2 * 256 + threadIdx.x];
    __syncthreads();
    float acc = 0.f;
#pragma unroll 4
    for (int o = 0; o < 256; ++o) {
        acc += vps[o] * proj_w[(size_t)o * CD_ + c];
    }
    W2b[(size_t)o2 * CD_ + c] = f2bf(acc);
}

// ---------------- fp32 -> bf16 elementwise ----------------
__global__ void cvt_kernel(const float* __restrict__ src, unsigned short* __restrict__ dst, int n) {
    int i = blockIdx.x * blockDim.x + threadIdx.x;
    if (i < n) dst[i] = f2bf(src[i]);
}

// ---------------- reference-point projection -> ref2d(v,q,2) ----------------
__global__ void ref2d_kernel(const float* __restrict__ l2i, float* __restrict__ ref2d) {
    int idx = blockIdx.x * blockDim.x + threadIdx.x;
    if (idx >= NVIEW * Q_TOT) return;
    int v = idx / Q_TOT, q = idx % Q_TOT;
    int wq = q % 100, hq = q / 100;
    float gx = (wq + 0.5f) * 0.01f;
    float gy = (hq + 0.5f) * 0.01f;
    float wx = gx * 102.4f - 51.2f;
    float wy = gy * 102.4f - 51.2f;
    const float* L = l2i + v * 16;
    float L0=L[0],L1=L[1],L2=L[2],L3=L[3],L4=L[4],L5=L[5],L6=L[6],L7=L[7];
    float L8=L[8],L9=L[9],L10=L[10],L11=L[11];
    float sw = 0.f, sx = 0.f, sy = 0.f;
#pragma unroll
    for (int d = 0; d < 4; ++d) {
        float zs = (0.5f + (float)d * (7.0f / 3.0f)) * 0.125f;
        float wz = zs * 8.0f - 5.0f;
        float c0 = L0 * wx + L1 * wy + L2 * wz + L3;
        float c1 = L4 * wx + L5 * wy + L6 * wz + L7;
        float c2 = L8 * wx + L9 * wy + L10 * wz + L11;
        bool bm = c2 > 1e-5f;
        float dc = fmaxf(c2, 1e-5f);
        float u  = (c0 / dc) * 0.5775f;
        float vv = (c1 / dc) * 0.5775f;
        bool in_img = (u >= 0.f) && (u <= 923.f) && (vv >= 0.f) && (vv <= 517.f);
        bool valid = bm && in_img;
        float refx = fminf(fmaxf(u / 923.0f, 0.f), 1.f);
        float refy = fminf(fmaxf(vv / 517.0f, 0.f), 1.f);
        float w = valid ? 1.0f : 1e-6f;
        sw += w; sx += refx * w; sy += refy * w;
    }
    float den = fmaxf(sw, 1e-6f);
    ref2d[(size_t)idx * 2 + 0] = sx / den;
    ref2d[(size_t)idx * 2 + 1] = sy / den;
}

// ---------------- concat so_w/aw_w into WQ(96,256), so_b/aw_b into bq(96) ----------------
__global__ void concat_kernel(const float* __restrict__ so_w, const float* __restrict__ so_b,
                              const float* __restrict__ aw_w, const float* __restrict__ aw_b,
                              float* __restrict__ WQ, float* __restrict__ bq) {
    int idx = blockIdx.x * blockDim.x + threadIdx.x;
    if (idx < 64 * 256) WQ[idx] = so_w[idx];
    else if (idx < 96 * 256) WQ[idx] = aw_w[idx - 64 * 256];
    if (idx < 64) bq[idx] = so_b[idx];
    else if (idx < 96) bq[idx] = aw_b[idx - 64];
}

// ---------------- tiled fp32 GEMM (kept for the small qout GEMM) ----------------
template <int MODE>
__global__ __launch_bounds__(256) void gemm_nt(const float* __restrict__ A,
                                               const float* __restrict__ B,
                                               const float* __restrict__ bias,
                                               float* __restrict__ C,
                                               int M, int N, int K) {
    __shared__ float As[16][68];
    __shared__ float Bs[16][68];
    int tid = threadIdx.x;
    int m0 = blockIdx.x * 64, n0 = blockIdx.y * 64;
    int r = tid >> 2, c4 = (tid & 3) * 4;
    int tm = (tid >> 4) * 4, tn = (tid & 15) * 4;
    float acc[4][4] = {};
    bool la = (m0 + r < M);
    bool lb = (n0 + r < N);
    const float* Arow = A + (size_t)(m0 + r) * K;
    const float* Brow = B + (size_t)(n0 + r) * K;
    for (int k0 = 0; k0 < K; k0 += 16) {
        float4 av = make_float4(0, 0, 0, 0), bv4 = make_float4(0, 0, 0, 0);
        if (la) av  = *(const float4*)(Arow + k0 + c4);
        if (lb) bv4 = *(const float4*)(Brow + k0 + c4);
        __syncthreads();
        As[c4 + 0][r] = av.x;  As[c4 + 1][r] = av.y;  As[c4 + 2][r] = av.z;  As[c4 + 3][r] = av.w;
        Bs[c4 + 0][r] = bv4.x; Bs[c4 + 1][r] = bv4.y; Bs[c4 + 2][r] = bv4.z; Bs[c4 + 3][r] = bv4.w;
        __syncthreads();
#pragma unroll
        for (int k = 0; k < 16; ++k) {
            float4 a = *(const float4*)&As[k][tm];
            float4 b = *(const float4*)&Bs[k][tn];
            float aa[4] = {a.x, a.y, a.z, a.w};
            float bb[4] = {b.x, b.y, b.z, b.w};
#pragma unroll
            for (int i = 0; i < 4; ++i)
#pragma unroll
                for (int j = 0; j < 4; ++j)
                    acc[i][j] += aa[i] * bb[j];
        }
    }
    int n = n0 + tn;
    if (n < N) {
#pragma unroll
        for (int i = 0; i < 4; ++i) {
            int m = m0 + tm + i;
            if (m >= M) continue;
            float4 o;
            o.x = acc[i][0] + bias[n + 0];
            o.y = acc[i][1] + bias[n + 1];
            o.z = acc[i][2] + bias[n + 2];
            o.w = acc[i][3] + bias[n + 3];
            *(float4*)(C + (size_t)m * N + n) = o;
        }
    }
}

// ---------------- bf16 MFMA GEMM: C(M,256) = A(M,K)fp32 * Bw(256,K)bf16^T ----------------
// 64x64 tile per block (grid = (N/64, M/64)), 4 waves; wave owns 16-row slice x 64 cols.
// MODE 0: C[m*256+n] = acc + bias[n]                      (val path)
// MODE 1: C[n*M+m]   = acc + f*(bias[n] + resid[m*256+n]) (out path, transposed store)
// LDS tiles [row][64k] bf16 (128 B rows), chunk-XOR swizzle: chunk' = chunk ^ (row&7).
template <int MODE>
__global__ __launch_bounds__(256) void mfma_gemm(const float* __restrict__ A,
                                                 const unsigned short* __restrict__ Bw,
                                                 const float* __restrict__ bias,
                                                 const float* __restrict__ resid,
                                                 const float* __restrict__ wview,
                                                 float* __restrict__ C,
                                                 int M, int K) {
    __shared__ unsigned short As[64 * 64];
    __shared__ unsigned short Bs[64 * 64];
    char* Ab = (char*)As;
    char* Bb = (char*)Bs;
    int tid = threadIdx.x;
    int wid = tid >> 6, lane = tid & 63;
    int m0 = blockIdx.y * 64;
    int n0 = blockIdx.x * 64;
    int ar = tid >> 2, ag = tid & 3;      // A stage: row (0..63), col-group (16 fp32)
    int lr = lane & 15, lq = lane >> 4;

    f32x4 acc[4];
#pragma unroll
    for (int j = 0; j < 4; ++j) acc[j] = (f32x4)(0.f);

    float4 aReg[4];
    uint4 bReg[2];
    const int KT = K >> 6;

    auto LOADG = [&](int kt) {
        int k0 = kt << 6;
        bool av = (m0 + ar) < M;
        const float* ap = A + (size_t)(m0 + ar) * K + k0 + ag * 16;
#pragma unroll
        for (int r = 0; r < 4; ++r)
            aReg[r] = av ? *(const float4*)(ap + r * 4) : make_float4(0.f, 0.f, 0.f, 0.f);
#pragma unroll
        for (int i = 0; i < 2; ++i) {
            int L = tid + (i << 8);
            int row = L >> 3, c = L & 7;
            bReg[i] = *(const uint4*)(Bw + (size_t)(n0 + row) * K + k0 + c * 8);
        }
    };
    auto TOLDS = [&]() {
        unsigned u[8];
#pragma unroll
        for (int r = 0; r < 4; ++r) {
            const float* f = (const float*)&aReg[r];
            u[2 * r]     = (unsigned)f2bf(f[0]) | ((unsigned)f2bf(f[1]) << 16);
            u[2 * r + 1] = (unsigned)f2bf(f[2]) | ((unsigned)f2bf(f[3]) << 16);
        }
        uint4 w0 = make_uint4(u[0], u[1], u[2], u[3]);
        uint4 w1 = make_uint4(u[4], u[5], u[6], u[7]);
        *(uint4*)(Ab + ar * 128 + (((2 * ag) ^ (ar & 7)) << 4)) = w0;
        *(uint4*)(Ab + ar * 128 + (((2 * ag + 1) ^ (ar & 7)) << 4)) = w1;
#pragma unroll
        for (int i = 0; i < 2; ++i) {
            int L = tid + (i << 8);
            int row = L >> 3, c = L & 7;
            *(uint4*)(Bb + row * 128 + ((c ^ (row & 7)) << 4)) = bReg[i];
        }
    };

    LOADG(0);
    for (int kt = 0; kt < KT; ++kt) {
        TOLDS();
        __syncthreads();
        if (kt + 1 < KT) LOADG(kt + 1);
#pragma unroll
        for (int s = 0; s < 2; ++s) {
            int chunk = (s << 2) + lq;
            int arow = (wid << 4) + lr;
            bf16x8 af = *(bf16x8*)(Ab + arow * 128 + ((chunk ^ (arow & 7)) << 4));
#pragma unroll
            for (int j = 0; j < 4; ++j) {
                int brow = (j << 4) + lr;
                bf16x8 bfr = *(bf16x8*)(Bb + brow * 128 + ((chunk ^ (brow & 7)) << 4));
                acc[j] = __builtin_amdgcn_mfma_f32_16x16x32_bf16(af, bfr, acc[j], 0, 0, 0);
            }
        }
        __syncthreads();
    }

    if (MODE == 0) {
        int mb = m0 + (wid << 4) + (lq << 2);
#pragma unroll
        for (int j = 0; j < 4; ++j) {
            int n = n0 + (j << 4) + lr;
            float bn = bias[n];
#pragma unroll
            for (int e = 0; e < 4; ++e) {
                int m = mb + e;
                if (m < M) C[(size_t)m * 256 + n] = acc[j][e] + bn;
            }
        }
    } else {
        float s = 0.f;
#pragma unroll
        for (int v = 0; v < 6; ++v) {
            float x = wview[v];
            s += (x > 20.f) ? x : log1pf(expf(x));
        }
        float f = s / fmaxf(s, 1e-6f);
        int mb = m0 + (wid << 4) + (lq << 2);
#pragma unroll
        for (int j = 0; j < 4; ++j) {
            int n = n0 + (j << 4) + lr;
            float bn = bias[n];
            if (mb + 4 <= M) {
                float4 o;
                float* oo = (float*)&o;
#pragma unroll
                for (int e = 0; e < 4; ++e)
                    oo[e] = acc[j][e] + f * (bn + resid[(size_t)(mb + e) * 256 + n]);
                *(float4*)(C + (size_t)n * M + mb) = o;
            } else {
#pragma unroll
                for (int e = 0; e < 4; ++e) {
                    int m = mb + e;
                    if (m < M) C[(size_t)n * M + m] = acc[j][e] + f * (bn + resid[(size_t)m * 256 + n]);
                }
            }
        }
    }
}

// ---------------- deformable sampling, vectorized gather ----------------
__global__ __launch_bounds__(256) void sample_kernel(const float* __restrict__ val,
                                                     const float* __restrict__ ref2d,
                                                     const float* __restrict__ qout,
                                                     const float* __restrict__ wview,
                                                     float* __restrict__ sampavg) {
    __shared__ uint4  sOff[4 * 240];
    __shared__ float4 sW[4 * 240];
    int tid = threadIdx.x;
    int qb = blockIdx.x * 4;

    float sp[6]; float swv = 0.f;
#pragma unroll
    for (int vv = 0; vv < NVIEW; ++vv) {
        float x = wview[vv];
        float spv = (x > 20.f) ? x : log1pf(expf(x));
        sp[vv] = spv; swv += spv;
    }
    float inv_swv = 1.0f / fmaxf(swv, 1e-6f);

#pragma unroll
    for (int t = tid; t < 768; t += 256) {
        int ql = t / 192;
        int rem = t - ql * 192;
        int v = rem >> 5;
        int h = (rem >> 2) & 7;
        int p = rem & 3;
        int q = qb + ql;
        const float* qo = qout + (size_t)q * 96;
        float ox = qo[h * 8 + 2 * p];
        float oy = qo[h * 8 + 2 * p + 1];
        float a0 = qo[64 + h * 4 + 0];
        float a1 = qo[64 + h * 4 + 1];
        float a2 = qo[64 + h * 4 + 2];
        float a3 = qo[64 + h * 4 + 3];
        float mx = fmaxf(fmaxf(a0, a1), fmaxf(a2, a3));
        float e0 = expf(a0 - mx), e1 = expf(a1 - mx), e2 = expf(a2 - mx), e3 = expf(a3 - mx);
        float esum = e0 + e1 + e2 + e3;
        float ep = (p == 0) ? e0 : (p == 1) ? e1 : (p == 2) ? e2 : e3;
        float scale = (ep / esum) * sp[v] * inv_swv;

        float rx = ref2d[(size_t)(v * Q_TOT + q) * 2 + 0];
        float ry = ref2d[(size_t)(v * Q_TOT + q) * 2 + 1];
        float x = (rx + ox / 66.0f) * 66.0f - 0.5f;
        float y = (ry + oy / 37.0f) * 37.0f - 0.5f;
        float xf = floorf(x), yf = floorf(y);
        float fx = x - xf, fy = y - yf;
        int xi = (int)xf, yi = (int)yf;

        float cw[4] = { (1.f - fx) * (1.f - fy), fx * (1.f - fy), (1.f - fx) * fy, fx * fy };
        unsigned off[4];
#pragma unroll
        for (int cyi = 0; cyi < 2; ++cyi) {
#pragma unroll
            for (int cxi = 0; cxi < 2; ++cxi) {
                int cx = xi + cxi, cy = yi + cyi;
                bool ok = (cx >= 0) && (cx < WP_) && (cy >= 0) && (cy < HP_);
                int ccx = cx < 0 ? 0 : (cx > WP_ - 1 ? WP_ - 1 : cx);
                int ccy = cy < 0 ? 0 : (cy > HP_ - 1 ? HP_ - 1 : cy);
                int c_ = cyi * 2 + cxi;
                off[c_] = (unsigned)((v * NTOK + ccy * WP_ + ccx) << 10);
                cw[c_] = ok ? cw[c_] * scale : 0.f;
            }
        }
        int slot = ql * 240 + v * 40 + h * 5 + p;
        sOff[slot] = make_uint4(off[0], off[1], off[2], off[3]);
        sW[slot]   = make_float4(cw[0], cw[1], cw[2], cw[3]);
    }
    __syncthreads();

    int ql = tid >> 6;
    int lane = tid & 63;
    int h = lane >> 3, d4 = (lane & 7) << 2;
    unsigned coff = (unsigned)((h * 32 + d4) << 2);
    const char* vbase = (const char*)val;
    float acc0 = 0.f, acc1 = 0.f, acc2 = 0.f, acc3 = 0.f;
#pragma unroll
    for (int v = 0; v < NVIEW; ++v) {
#pragma unroll
        for (int p = 0; p < 4; ++p) {
            int slot = ql * 240 + v * 40 + h * 5 + p;
            uint4 off = sOff[slot];
            float4 w = sW[slot];
            float4 g0 = *(const float4*)(vbase + (off.x + coff));
            float4 g1 = *(const float4*)(vbase + (off.y + coff));
            float4 g2 = *(const float4*)(vbase + (off.z + coff));
            float4 g3 = *(const float4*)(vbase + (off.w + coff));
            acc0 += w.x * g0.x + w.y * g1.x + w.z * g2.x + w.w * g3.x;
            acc1 += w.x * g0.y + w.y * g1.y + w.z * g2.y + w.w * g3.y;
            acc2 += w.x * g0.z + w.y * g1.z + w.z * g2.z + w.w * g3.z;
            acc3 += w.x * g0.w + w.y * g1.w + w.z * g2.w + w.w * g3.w;
        }
    }
    int q = qb + ql;
    *(float4*)(sampavg + (size_t)q * CC_ + h * 32 + d4) = make_float4(acc0, acc1, acc2, acc3);
}

extern "C" void kernel_launch(void* const* d_in, const int* in_sizes, int n_in,
                              void* d_out, int out_size, void* d_ws, size_t ws_size,
                              hipStream_t stream) {
    const float* lt   = (const float*)d_in[0];
    const float* l2i  = (const float*)d_in[1];
    const float* proj = (const float*)d_in[2];
    const float* bqq  = (const float*)d_in[3];
    const float* wv   = (const float*)d_in[4];
    const float* vpw  = (const float*)d_in[5];
    const float* vpb  = (const float*)d_in[6];
    const float* sow  = (const float*)d_in[7];
    const float* sob  = (const float*)d_in[8];
    const float* aww  = (const float*)d_in[9];
    const float* awb  = (const float*)d_in[10];
    const float* opw  = (const float*)d_in[11];
    const float* opb  = (const float*)d_in[12];
    float* out = (float*)d_out;

    unsigned short* W2b  = (unsigned short*)d_ws;        // 256*768 ushort
    unsigned short* opwb = W2b + 256 * 768;              // 256*256 ushort
    float* base    = (float*)d_ws + 98304 + 32768;
    float* val     = base;                               // 14652*256
    float* ref2d   = val + 14652 * 256;                  // 60000*2
    float* WQ      = ref2d + 120000;                     // 96*256
    float* bq      = WQ + 96 * 256;                      // 96 (pad 128)
    float* qout    = bq + 128;                           // 10000*96
    float* sampavg = qout + 10000 * 96;                  // 10000*256

    hipLaunchKernelGGL(w2_kernel, dim3(768), dim3(256), 0, stream, vpw, proj, W2b);
    hipLaunchKernelGGL(cvt_kernel, dim3(256), dim3(256), 0, stream, opw, opwb, 256 * 256);
    hipLaunchKernelGGL(ref2d_kernel, dim3((NVIEW * Q_TOT + 255) / 256), dim3(256), 0, stream, l2i, ref2d);
    hipLaunchKernelGGL(concat_kernel, dim3(96), dim3(256), 0, stream, sow, sob, aww, awb, WQ, bq);
    // qout = bev_query @ WQ^T + bq : M=10000, N=96, K=256 (fp32 path)
    hipLaunchKernelGGL((gemm_nt<0>), dim3(157, 2), dim3(256), 0, stream,
                       bqq, WQ, bq, qout, Q_TOT, 96, 256);
    // val = last_tokens @ W2b^T + vp_b : M=14652, K=768 (bf16 MFMA, 64x64 tiles)
    hipLaunchKernelGGL((mfma_gemm<0>), dim3(4, 229), dim3(256), 0, stream,
                       lt, W2b, vpb, nullptr, nullptr, val, 14652, 768);
    hipLaunchKernelGGL(sample_kernel, dim3(Q_TOT / 4), dim3(256), 0, stream,
                       val, ref2d, qout, wv, sampavg);
    // out(256,10000) = transpose(sampavg @ opwb^T + f*(op_b + query)) : M=10000, K=256 (bf16 MFMA)
    hipLaunchKernelGGL((mfma_gemm<1>), dim3(4, 157), dim3(256), 0, stream,
                       sampavg, opwb, opb, bqq, wv, out, Q_TOT, 256);
}

// Round 6
// 151.859 us; speedup vs baseline: 1.0663x; 1.0663x over previous
//
#include <hip/hip_runtime.h>
#include <math.h>

#define Q_TOT 10000
#define NVIEW 6
#define NTOK  2442
#define HP_   37
#define WP_   66
#define CD_   768
#define CC_   256

typedef __attribute__((ext_vector_type(8))) short bf16x8;
typedef __attribute__((ext_vector_type(4))) float f32x4;

__device__ inline unsigned f2bf(float f) {
    unsigned u = __builtin_bit_cast(unsigned, f);
    unsigned r = u + 0x7FFFu + ((u >> 16) & 1u);
    return r >> 16;
}

// ---------------- W2 = vp_w(256,256) @ proj_w(256,768), output bf16 ----------------
__global__ __launch_bounds__(256) void w2_kernel(const float* __restrict__ vp_w,
                                                 const float* __restrict__ proj_w,
                                                 unsigned short* __restrict__ W2b) {
    int b = blockIdx.x;            // 0..767
    int o2 = b / 3;
    int c = (b % 3) * 256 + threadIdx.x;
    __shared__ float vps[256];
    vps[threadIdx.x] = vp_w[(size_t)o2 * 256 + threadIdx.x];
    __syncthreads();
    float acc = 0.f;
#pragma unroll 4
    for (int o = 0; o < 256; ++o) {
        acc += vps[o] * proj_w[(size_t)o * CD_ + c];
    }
    W2b[(size_t)o2 * CD_ + c] = (unsigned short)f2bf(acc);
}

// ---------------- fp32 -> bf16, 8 elems/thread ----------------
__global__ void cvt8_kernel(const float* __restrict__ src, unsigned short* __restrict__ dst, int n8) {
    int i = blockIdx.x * blockDim.x + threadIdx.x;
    if (i >= n8) return;
    float4 a = *(const float4*)(src + (size_t)i * 8);
    float4 b = *(const float4*)(src + (size_t)i * 8 + 4);
    uint4 o;
    o.x = f2bf(a.x) | (f2bf(a.y) << 16);
    o.y = f2bf(a.z) | (f2bf(a.w) << 16);
    o.z = f2bf(b.x) | (f2bf(b.y) << 16);
    o.w = f2bf(b.z) | (f2bf(b.w) << 16);
    *(uint4*)(dst + (size_t)i * 8) = o;
}

// ---------------- reference-point projection -> ref2d(v,q,2) ----------------
__global__ void ref2d_kernel(const float* __restrict__ l2i, float* __restrict__ ref2d) {
    int idx = blockIdx.x * blockDim.x + threadIdx.x;
    if (idx >= NVIEW * Q_TOT) return;
    int v = idx / Q_TOT, q = idx % Q_TOT;
    int wq = q % 100, hq = q / 100;
    float gx = (wq + 0.5f) * 0.01f;
    float gy = (hq + 0.5f) * 0.01f;
    float wx = gx * 102.4f - 51.2f;
    float wy = gy * 102.4f - 51.2f;
    const float* L = l2i + v * 16;
    float L0=L[0],L1=L[1],L2=L[2],L3=L[3],L4=L[4],L5=L[5],L6=L[6],L7=L[7];
    float L8=L[8],L9=L[9],L10=L[10],L11=L[11];
    float sw = 0.f, sx = 0.f, sy = 0.f;
#pragma unroll
    for (int d = 0; d < 4; ++d) {
        float zs = (0.5f + (float)d * (7.0f / 3.0f)) * 0.125f;
        float wz = zs * 8.0f - 5.0f;
        float c0 = L0 * wx + L1 * wy + L2 * wz + L3;
        float c1 = L4 * wx + L5 * wy + L6 * wz + L7;
        float c2 = L8 * wx + L9 * wy + L10 * wz + L11;
        bool bm = c2 > 1e-5f;
        float dc = fmaxf(c2, 1e-5f);
        float u  = (c0 / dc) * 0.5775f;
        float vv = (c1 / dc) * 0.5775f;
        bool in_img = (u >= 0.f) && (u <= 923.f) && (vv >= 0.f) && (vv <= 517.f);
        bool valid = bm && in_img;
        float refx = fminf(fmaxf(u / 923.0f, 0.f), 1.f);
        float refy = fminf(fmaxf(vv / 517.0f, 0.f), 1.f);
        float w = valid ? 1.0f : 1e-6f;
        sw += w; sx += refx * w; sy += refy * w;
    }
    float den = fmaxf(sw, 1e-6f);
    ref2d[(size_t)idx * 2 + 0] = sx / den;
    ref2d[(size_t)idx * 2 + 1] = sy / den;
}

// ---------------- build WQb(128,256) bf16 zero-padded + bqp(128) ----------------
__global__ void concatb_kernel(const float* __restrict__ so_w, const float* __restrict__ so_b,
                               const float* __restrict__ aw_w, const float* __restrict__ aw_b,
                               unsigned short* __restrict__ WQb, float* __restrict__ bqp) {
    int row = blockIdx.x, col = threadIdx.x;
    float v = (row < 64) ? so_w[row * 256 + col] : (row < 96 ? aw_w[(row - 64) * 256 + col] : 0.f);
    WQb[row * 256 + col] = (unsigned short)f2bf(v);
    if (row == 0 && col < 128) bqp[col] = (col < 64) ? so_b[col] : (col < 96 ? aw_b[col - 64] : 0.f);
}

// ---------------- bf16 MFMA GEMM, 64x64 tile, XCD-chunked swizzle ----------------
// MODE 0: A fp32 (convert on stage), C[m*256+n]=acc+bias[n]         (val)
// MODE 1: A bf16,  C[n*M+m]=acc+f*(bias[n]+resid[m*256+n])          (out, transposed)
// MODE 2: A bf16,  C[m*96+n]=acc+bias[n] for n<96                   (qout)
template <int MODE>
__global__ __launch_bounds__(256) void mfma_gemm(const void* __restrict__ Aptr,
                                                 const unsigned short* __restrict__ Bw,
                                                 const float* __restrict__ bias,
                                                 const float* __restrict__ resid,
                                                 const float* __restrict__ wview,
                                                 float* __restrict__ C,
                                                 int M, int K, int nt_shift) {
    __shared__ unsigned short As_[64 * 64];
    __shared__ unsigned short Bs_[64 * 64];
    char* Ab = (char*)As_;
    char* Bb = (char*)Bs_;
    int tid = threadIdx.x;
    int wid = tid >> 6, lane = tid & 63;

    // bijective XCD-chunked swizzle: consecutive wgids (same m-tile's n-tiles) on one XCD
    int nwg = gridDim.x;
    int bid = blockIdx.x;
    int qd = nwg >> 3, r = nwg & 7;
    int xcd = bid & 7, seq = bid >> 3;
    int wgid = (xcd < r) ? (xcd * (qd + 1) + seq) : (r * (qd + 1) + (xcd - r) * qd + seq);
    int mt = wgid >> nt_shift;
    int nt = wgid & ((1 << nt_shift) - 1);
    int m0 = mt * 64, n0 = nt * 64;

    int lr = lane & 15, lq = lane >> 4;
    f32x4 acc[4];
#pragma unroll
    for (int j = 0; j < 4; ++j) acc[j] = (f32x4)(0.f);

    const int KT = K >> 6;
    // staging registers
    float4 aRegF[4];            // MODE 0 (fp32 A)
    uint4 aRegB[2];             // MODE 1/2 (bf16 A)
    uint4 bReg[2];
    int ar = tid >> 2, ag = tid & 3;   // fp32 A staging decomposition
    const float* Af = (const float*)Aptr;
    const unsigned short* Ah = (const unsigned short*)Aptr;

    auto LOADG = [&](int kt) {
        int k0 = kt << 6;
        if (MODE == 0) {
            bool av = (m0 + ar) < M;
            const float* ap = Af + (size_t)(m0 + ar) * K + k0 + ag * 16;
#pragma unroll
            for (int rr = 0; rr < 4; ++rr)
                aRegF[rr] = av ? *(const float4*)(ap + rr * 4) : make_float4(0.f, 0.f, 0.f, 0.f);
        } else {
#pragma unroll
            for (int i = 0; i < 2; ++i) {
                int s = tid + (i << 8);
                int row = s >> 3, c = s & 7;
                aRegB[i] = *(const uint4*)(Ah + (size_t)(m0 + row) * K + k0 + c * 8);
            }
        }
#pragma unroll
        for (int i = 0; i < 2; ++i) {
            int s = tid + (i << 8);
            int row = s >> 3, c = s & 7;
            bReg[i] = *(const uint4*)(Bw + (size_t)(n0 + row) * K + k0 + c * 8);
        }
    };
    auto TOLDS = [&]() {
        if (MODE == 0) {
            unsigned u[8];
#pragma unroll
            for (int rr = 0; rr < 4; ++rr) {
                const float* f = (const float*)&aRegF[rr];
                u[2 * rr]     = f2bf(f[0]) | (f2bf(f[1]) << 16);
                u[2 * rr + 1] = f2bf(f[2]) | (f2bf(f[3]) << 16);
            }
            *(uint4*)(Ab + ar * 128 + (((2 * ag) ^ (ar & 7)) << 4))     = make_uint4(u[0], u[1], u[2], u[3]);
            *(uint4*)(Ab + ar * 128 + (((2 * ag + 1) ^ (ar & 7)) << 4)) = make_uint4(u[4], u[5], u[6], u[7]);
        } else {
#pragma unroll
            for (int i = 0; i < 2; ++i) {
                int s = tid + (i << 8);
                int row = s >> 3, c = s & 7;
                *(uint4*)(Ab + row * 128 + ((c ^ (row & 7)) << 4)) = aRegB[i];
            }
        }
#pragma unroll
        for (int i = 0; i < 2; ++i) {
            int s = tid + (i << 8);
            int row = s >> 3, c = s & 7;
            *(uint4*)(Bb + row * 128 + ((c ^ (row & 7)) << 4)) = bReg[i];
        }
    };

    LOADG(0);
    for (int kt = 0; kt < KT; ++kt) {
        TOLDS();
        __syncthreads();
        if (kt + 1 < KT) LOADG(kt + 1);
#pragma unroll
        for (int s = 0; s < 2; ++s) {
            int chunk = (s << 2) + lq;
            int arow = (wid << 4) + lr;
            bf16x8 af = *(bf16x8*)(Ab + arow * 128 + ((chunk ^ (arow & 7)) << 4));
#pragma unroll
            for (int j = 0; j < 4; ++j) {
                int brow = (j << 4) + lr;
                bf16x8 bfr = *(bf16x8*)(Bb + brow * 128 + ((chunk ^ (brow & 7)) << 4));
                acc[j] = __builtin_amdgcn_mfma_f32_16x16x32_bf16(af, bfr, acc[j], 0, 0, 0);
            }
        }
        __syncthreads();
    }

    int mb = m0 + (wid << 4) + (lq << 2);
    if (MODE == 0) {
#pragma unroll
        for (int j = 0; j < 4; ++j) {
            int n = n0 + (j << 4) + lr;
            float bn = bias[n];
#pragma unroll
            for (int e = 0; e < 4; ++e) {
                int m = mb + e;
                if (m < M) C[(size_t)m * 256 + n] = acc[j][e] + bn;
            }
        }
    } else if (MODE == 1) {
        float s = 0.f;
#pragma unroll
        for (int v = 0; v < 6; ++v) {
            float x = wview[v];
            s += (x > 20.f) ? x : log1pf(expf(x));
        }
        float f = s / fmaxf(s, 1e-6f);
#pragma unroll
        for (int j = 0; j < 4; ++j) {
            int n = n0 + (j << 4) + lr;
            float bn = bias[n];
            if (mb + 4 <= M) {
                float4 o;
                float* oo = (float*)&o;
#pragma unroll
                for (int e = 0; e < 4; ++e)
                    oo[e] = acc[j][e] + f * (bn + resid[(size_t)(mb + e) * 256 + n]);
                *(float4*)(C + (size_t)n * M + mb) = o;
            } else {
#pragma unroll
                for (int e = 0; e < 4; ++e) {
                    int m = mb + e;
                    if (m < M) C[(size_t)n * M + m] = acc[j][e] + f * (bn + resid[(size_t)m * 256 + n]);
                }
            }
        }
    } else {
#pragma unroll
        for (int j = 0; j < 4; ++j) {
            int n = n0 + (j << 4) + lr;
            if (n >= 96) continue;
            float bn = bias[n];
#pragma unroll
            for (int e = 0; e < 4; ++e) {
                int m = mb + e;
                if (m < M) C[(size_t)m * 96 + n] = acc[j][e] + bn;
            }
        }
    }
}

// ---------------- deformable sampling, vectorized gather, bf16 output ----------------
__global__ __launch_bounds__(256) void sample_kernel(const float* __restrict__ val,
                                                     const float* __restrict__ ref2d,
                                                     const float* __restrict__ qout,
                                                     const float* __restrict__ wview,
                                                     unsigned short* __restrict__ sampavgB) {
    __shared__ uint4  sOff[4 * 240];
    __shared__ float4 sW[4 * 240];
    int tid = threadIdx.x;
    int qb = blockIdx.x * 4;

    float sp[6]; float swv = 0.f;
#pragma unroll
    for (int vv = 0; vv < NVIEW; ++vv) {
        float x = wview[vv];
        float spv = (x > 20.f) ? x : log1pf(expf(x));
        sp[vv] = spv; swv += spv;
    }
    float inv_swv = 1.0f / fmaxf(swv, 1e-6f);

#pragma unroll
    for (int t = tid; t < 768; t += 256) {
        int ql = t / 192;
        int rem = t - ql * 192;
        int v = rem >> 5;
        int h = (rem >> 2) & 7;
        int p = rem & 3;
        int q = qb + ql;
        const float* qo = qout + (size_t)q * 96;
        float ox = qo[h * 8 + 2 * p];
        float oy = qo[h * 8 + 2 * p + 1];
        float a0 = qo[64 + h * 4 + 0];
        float a1 = qo[64 + h * 4 + 1];
        float a2 = qo[64 + h * 4 + 2];
        float a3 = qo[64 + h * 4 + 3];
        float mx = fmaxf(fmaxf(a0, a1), fmaxf(a2, a3));
        float e0 = expf(a0 - mx), e1 = expf(a1 - mx), e2 = expf(a2 - mx), e3 = expf(a3 - mx);
        float esum = e0 + e1 + e2 + e3;
        float ep = (p == 0) ? e0 : (p == 1) ? e1 : (p == 2) ? e2 : e3;
        float scale = (ep / esum) * sp[v] * inv_swv;

        float rx = ref2d[(size_t)(v * Q_TOT + q) * 2 + 0];
        float ry = ref2d[(size_t)(v * Q_TOT + q) * 2 + 1];
        float x = (rx + ox / 66.0f) * 66.0f - 0.5f;
        float y = (ry + oy / 37.0f) * 37.0f - 0.5f;
        float xf = floorf(x), yf = floorf(y);
        float fx = x - xf, fy = y - yf;
        int xi = (int)xf, yi = (int)yf;

        float cw[4] = { (1.f - fx) * (1.f - fy), fx * (1.f - fy), (1.f - fx) * fy, fx * fy };
        unsigned off[4];
#pragma unroll
        for (int cyi = 0; cyi < 2; ++cyi) {
#pragma unroll
            for (int cxi = 0; cxi < 2; ++cxi) {
                int cx = xi + cxi, cy = yi + cyi;
                bool ok = (cx >= 0) && (cx < WP_) && (cy >= 0) && (cy < HP_);
                int ccx = cx < 0 ? 0 : (cx > WP_ - 1 ? WP_ - 1 : cx);
                int ccy = cy < 0 ? 0 : (cy > HP_ - 1 ? HP_ - 1 : cy);
                int c_ = cyi * 2 + cxi;
                off[c_] = (unsigned)((v * NTOK + ccy * WP_ + ccx) << 10);
                cw[c_] = ok ? cw[c_] * scale : 0.f;
            }
        }
        int slot = ql * 240 + v * 40 + h * 5 + p;
        sOff[slot] = make_uint4(off[0], off[1], off[2], off[3]);
        sW[slot]   = make_float4(cw[0], cw[1], cw[2], cw[3]);
    }
    __syncthreads();

    int ql = tid >> 6;
    int lane = tid & 63;
    int h = lane >> 3, d4 = (lane & 7) << 2;
    unsigned coff = (unsigned)((h * 32 + d4) << 2);
    const char* vbase = (const char*)val;
    float acc0 = 0.f, acc1 = 0.f, acc2 = 0.f, acc3 = 0.f;
#pragma unroll
    for (int v = 0; v < NVIEW; ++v) {
#pragma unroll
        for (int p = 0; p < 4; ++p) {
            int slot = ql * 240 + v * 40 + h * 5 + p;
            uint4 off = sOff[slot];
            float4 w = sW[slot];
            float4 g0 = *(const float4*)(vbase + (off.x + coff));
            float4 g1 = *(const float4*)(vbase + (off.y + coff));
            float4 g2 = *(const float4*)(vbase + (off.z + coff));
            float4 g3 = *(const float4*)(vbase + (off.w + coff));
            acc0 += w.x * g0.x + w.y * g1.x + w.z * g2.x + w.w * g3.x;
            acc1 += w.x * g0.y + w.y * g1.y + w.z * g2.y + w.w * g3.y;
            acc2 += w.x * g0.z + w.y * g1.z + w.z * g2.z + w.w * g3.z;
            acc3 += w.x * g0.w + w.y * g1.w + w.z * g2.w + w.w * g3.w;
        }
    }
    int q = qb + ql;
    unsigned u0 = f2bf(acc0) | (f2bf(acc1) << 16);
    unsigned u1 = f2bf(acc2) | (f2bf(acc3) << 16);
    *(uint2*)(sampavgB + (size_t)q * CC_ + h * 32 + d4) = make_uint2(u0, u1);
}

extern "C" void kernel_launch(void* const* d_in, const int* in_sizes, int n_in,
                              void* d_out, int out_size, void* d_ws, size_t ws_size,
                              hipStream_t stream) {
    const float* lt   = (const float*)d_in[0];
    const float* l2i  = (const float*)d_in[1];
    const float* proj = (const float*)d_in[2];
    const float* bqq  = (const float*)d_in[3];
    const float* wv   = (const float*)d_in[4];
    const float* vpw  = (const float*)d_in[5];
    const float* vpb  = (const float*)d_in[6];
    const float* sow  = (const float*)d_in[7];
    const float* sob  = (const float*)d_in[8];
    const float* aww  = (const float*)d_in[9];
    const float* awb  = (const float*)d_in[10];
    const float* opw  = (const float*)d_in[11];
    const float* opb  = (const float*)d_in[12];
    float* out = (float*)d_out;

    char* ws = (char*)d_ws;
    unsigned short* W2b   = (unsigned short*)(ws);             // 256*768*2   = 393216
    unsigned short* opwb  = (unsigned short*)(ws + 393216);    // 256*256*2   = 131072
    unsigned short* WQb   = (unsigned short*)(ws + 524288);    // 128*256*2   = 65536
    float*          bqp   = (float*)(ws + 589824);             // 128*4       = 512
    float*          ref2d = (float*)(ws + 590336);             // 60000*2*4   = 480000
    float*          qout  = (float*)(ws + 1070336);            // 10000*96*4  = 3840000
    float*          val   = (float*)(ws + 4910336);            // 14652*256*4 = 15003648
    unsigned short* Qb    = (unsigned short*)(ws + 19913984);  // 10048*256*2 = 5144576
    unsigned short* sampavgB = Qb;  // alias: Qb dead after qout GEMM, sampavgB written after

    hipLaunchKernelGGL(w2_kernel, dim3(768), dim3(256), 0, stream, vpw, proj, W2b);
    hipLaunchKernelGGL(cvt8_kernel, dim3(32), dim3(256), 0, stream, opw, opwb, 8192);
    hipLaunchKernelGGL(cvt8_kernel, dim3(1250), dim3(256), 0, stream, bqq, Qb, 320000);
    hipLaunchKernelGGL(ref2d_kernel, dim3((NVIEW * Q_TOT + 255) / 256), dim3(256), 0, stream, l2i, ref2d);
    hipLaunchKernelGGL(concatb_kernel, dim3(128), dim3(256), 0, stream, sow, sob, aww, awb, WQb, bqp);
    // qout = bev_query @ WQ^T + bq : M=10000, K=256, N-tiles=2 (bf16 MFMA)
    hipLaunchKernelGGL((mfma_gemm<2>), dim3(314), dim3(256), 0, stream,
                       (const void*)Qb, WQb, bqp, nullptr, nullptr, qout, Q_TOT, 256, 1);
    // val = last_tokens @ W2b^T + vp_b : M=14652, K=768, N-tiles=4
    hipLaunchKernelGGL((mfma_gemm<0>), dim3(916), dim3(256), 0, stream,
                       (const void*)lt, W2b, vpb, nullptr, nullptr, val, 14652, 768, 2);
    hipLaunchKernelGGL(sample_kernel, dim3(Q_TOT / 4), dim3(256), 0, stream,
                       val, ref2d, qout, wv, sampavgB);
    // out(256,10000) = transpose(sampavgB @ opwb^T + f*(op_b + query)) : M=10000, K=256
    hipLaunchKernelGGL((mfma_gemm<1>), dim3(628), dim3(256), 0, stream,
                       (const void*)sampavgB, opwb, opb, bqq, wv, out, Q_TOT, 256, 2);
}